// Round 6
// baseline (254.892 us; speedup 1.0000x reference)
//
#include <hip/hip_runtime.h>
#include <hip/hip_bf16.h>

typedef __hip_bfloat16 bf16;
typedef __attribute__((ext_vector_type(8))) short short8;   // 8 bf16 (4 VGPRs)
typedef __attribute__((ext_vector_type(4))) float f32x4;    // 4 fp32 acc

#define PI2 6.283185307179586f
#define EPSV 1e-5f

__device__ __forceinline__ short f2bs(float f){
  bf16 h = __float2bfloat16(f);
  short s; __builtin_memcpy(&s, &h, 2); return s;
}
__device__ __forceinline__ float s2f(short s){
  bf16 h; __builtin_memcpy(&h, &s, 2); return __bfloat162float(h);
}
__device__ __forceinline__ float4 f4add(float4 a, float4 b){ return make_float4(a.x+b.x, a.y+b.y, a.z+b.z, a.w+b.w); }
__device__ __forceinline__ float4 f4sub(float4 a, float4 b){ return make_float4(a.x-b.x, a.y-b.y, a.z-b.z, a.w-b.w); }

// ------ Prep+ydft merged: blocks [0,512) ydft | [512,1024) FWT | rest misc ---
// Y layout is now [b][ky][m][i] so k_xdft reads stream contiguously.
__global__ __launch_bounds__(256) void k_prep_ydft(
    const float* __restrict__ x, const float* __restrict__ z,
    const float* __restrict__ fw1, const float* __restrict__ fw2,
    float2* __restrict__ FWT,
    const float* __restrict__ b_l1w, const float* __restrict__ b_l1b,
    const float* __restrict__ b_l2w, const float* __restrict__ b_l2b,
    const float* __restrict__ b_g1w, const float* __restrict__ b_g1b,
    const float* __restrict__ b_g2w, const float* __restrict__ b_g2b,
    const float* __restrict__ b_g3w, const float* __restrict__ b_g3b,
    const float* __restrict__ f_l1w, const float* __restrict__ f_l1b,
    const float* __restrict__ f_l2w, const float* __restrict__ f_l2b,
    const float* __restrict__ f_g1w, const float* __restrict__ f_g1b,
    const float* __restrict__ f_g2w, const float* __restrict__ f_g2b,
    const float* __restrict__ f_g3w, const float* __restrict__ f_g3b,
    short* __restrict__ W1g, short* __restrict__ W2g,
    float2* __restrict__ TWY, float2* __restrict__ TWX,
    float* __restrict__ PB, float* __restrict__ ST,
    float2* __restrict__ Y){
  __shared__ __align__(16) char sm[36864];
  int tid = threadIdx.x;
  int bi = blockIdx.x;
  if(bi < 512){
    // ---- ydft: radix-4 over n; PQ/RS packed; on-the-fly twiddles ----
    float2 (*PQ)[64] = (float2(*)[64])sm;              // 16KB
    float2 (*RS)[64] = (float2(*)[64])(sm + 16384);    // 16KB
    float4 (*twl)[32] = (float4(*)[32])(sm + 32768);   // 4KB [kq2][np], kq2<8
    int b = bi >> 7, m = bi & 127;
    const float4* xp = (const float4*)(x + ((size_t)(b*128 + m)*128)*64);
    const float4* zp = (const float4*)(z + ((size_t)((b*2 + 0)*128 + m)*128)*64);
    int i4 = tid & 15, n0 = tid >> 4;
    #pragma unroll
    for(int it = 0; it < 2; it++){
      int np = n0 + it*16;
      float4 ea = f4sub(xp[np*16 + i4],      zp[np*16 + i4]);
      float4 eb = f4sub(xp[(np+32)*16 + i4], zp[(np+32)*16 + i4]);
      float4 ec = f4sub(xp[(np+64)*16 + i4], zp[(np+64)*16 + i4]);
      float4 ed = f4sub(xp[(np+96)*16 + i4], zp[(np+96)*16 + i4]);
      float4 sac = f4add(ea, ec), sbd = f4add(eb, ed);
      float4 P = f4add(sac, sbd), Q = f4sub(sac, sbd);
      float4 R = f4sub(ea, ec),  S = f4sub(eb, ed);
      *(float4*)&PQ[np][i4*4]     = make_float4(P.x, Q.x, P.y, Q.y);
      *(float4*)&PQ[np][i4*4 + 2] = make_float4(P.z, Q.z, P.w, Q.w);
      *(float4*)&RS[np][i4*4]     = make_float4(R.x, S.x, R.y, S.y);
      *(float4*)&RS[np][i4*4 + 2] = make_float4(R.z, S.z, R.w, S.w);
    }
    {
      int kq2 = tid >> 5, np = tid & 31;          // kq2 in [0,8)
      int ky0 = (kq2 >> 1)*4 + (kq2 & 1)*2;
      float s0, c0, s1, c1;
      sincosf(PI2*(float)((ky0*np) & 127)/128.f, &s0, &c0);
      sincosf(PI2*(float)(((ky0+1)*np) & 127)/128.f, &s1, &c1);
      twl[kq2][np] = make_float4(c0, s0, c1, s1);
    }
    __syncthreads();
    int i = tid & 63, kq = tid >> 6;
    float re[4] = {0,0,0,0}, im[4] = {0,0,0,0};
    for(int np = 0; np < 32; np++){
      float2 pq = PQ[np][i];
      float2 rs = RS[np][i];
      float4 t01 = twl[kq*2][np];
      float4 t23 = twl[kq*2 + 1][np];
      re[0] += pq.x*t01.x;               im[0] -= pq.x*t01.y;
      re[1] += rs.x*t01.z - rs.y*t01.w;  im[1] -= rs.y*t01.z + rs.x*t01.w;
      re[2] += pq.y*t23.x;               im[2] -= pq.y*t23.y;
      re[3] += rs.x*t23.z + rs.y*t23.w;  im[3] += rs.y*t23.z - rs.x*t23.w;
    }
    #pragma unroll
    for(int j = 0; j < 4; j++)
      Y[(((size_t)b*16 + kq*4 + j)*128 + m)*64 + i] = make_float2(re[j], im[j]);
    return;
  }
  if(bi < 1024){
    // ---- FWT transpose ----
    float (*Ls)[512] = (float(*)[512])sm;   // 32KB
    int bb = bi - 512;
    int arr = bb >> 8, rem = bb & 255;
    int i = rem >> 2, o0 = (rem & 3) * 16;
    const float* src = (arr ? fw2 : fw1) + ((size_t)(i*64 + o0))*512;
    for(int idx = tid; idx < 8192; idx += 256)
      Ls[idx >> 9][idx & 511] = src[idx];
    __syncthreads();
    int kxw = tid >> 4, ky = tid & 15;
    float2* dst = FWT + ((size_t)((arr*16 + kxw)*16 + ky))*4096 + i*64 + o0;
    for(int ol = 0; ol < 16; ol++)
      dst[ol] = make_float2(Ls[ol][tid*2], Ls[ol][tid*2 + 1]);
    return;
  }
  int i = (bi - 1024)*256 + tid;
  if(i < 32768){                         // W1g fragment layout
    int br = i >> 14, r = i & 16383;
    int fid = r >> 9, lane = (r >> 3) & 63, e = r & 7;
    int hb = fid & 1, t = (fid >> 1) & 3, ch = fid >> 3;
    int l15 = lane & 15, quad = lane >> 4;
    int n = ch*64 + t*16 + l15;
    int k = hb*32 + quad*8 + e;
    const float* src = br ? f_l1w : b_l1w;
    W1g[i] = f2bs(src[k*256 + n]);
    return;
  }
  i -= 32768;
  if(i < 32768){                         // W2g fragment layout
    int br = i >> 14, r = i & 16383;
    int fid = r >> 9, lane = (r >> 3) & 63, e = r & 7;
    int hb = fid & 1, t = (fid >> 1) & 3, ch = fid >> 3;
    int l15 = lane & 15, quad = lane >> 4;
    int n = t*16 + l15;
    int k = ch*64 + hb*32 + quad*8 + e;
    const float* src = br ? f_l2w : b_l2w;
    W2g[i] = f2bs(src[k*64 + n]);
    return;
  }
  i -= 32768;
  if(i < 2048){                          // TWY[ky][n]
    int ky = i >> 7, n = i & 127;
    float ang = PI2 * (float)((ky*n) & 127) / 128.0f;
    float s, c; sincosf(ang, &s, &c);
    TWY[i] = make_float2(c, s);
    return;
  }
  i -= 2048;
  if(i < 4096){                          // TWX[kp][m]
    int kp = i >> 7, m = i & 127;
    int kx = kp < 16 ? kp : 96 + kp;
    float ang = PI2 * (float)((kx*m) & 127) / 128.0f;
    float s, c; sincosf(ang, &s, &c);
    TWX[i] = make_float2(c, s);
    return;
  }
  i -= 4096;
  if(i < 384){ ST[i] = 0.f; return; }    // zero stats
  i -= 384;
  if(i < 2176){                          // param block
    int br = i >= 1088; int o = i - br*1088;
    float* pb = PB + br*2048;
    float v;
    if(o < 256)       v = (br ? f_l1b : b_l1b)[o];
    else if(o < 512)  v = (br ? f_g1w : b_g1w)[o-256];
    else if(o < 768)  v = (br ? f_g1b : b_g1b)[o-512];
    else if(o < 832)  v = (br ? f_l2b : b_l2b)[o-768];
    else if(o < 896)  v = (br ? f_g2w : b_g2w)[o-832];
    else if(o < 960)  v = (br ? f_g2b : b_g2b)[o-896];
    else if(o < 1024) v = (br ? f_g3w : b_g3w)[o-960];
    else              v = (br ? f_g3b : b_g3b)[o-1024];
    pb[o] = v;
  }
}

// ------- Stage 2: DFT over x, radix-2 over m, 4-way m-split, 512 thr --------
// Y layout [b][ky][m][i]: reads are contiguous 512-B rows, streamed.
__global__ __launch_bounds__(512) void k_xdft(const float2* __restrict__ Y,
                                              const float2* __restrict__ TWX,
                                              float2* __restrict__ X2){
  __shared__ float2 twl[16][64];
  __shared__ float sc[3][128][8];
  int bi = blockIdx.x;
  int b = bi >> 6, ky = (bi >> 2) & 15, half = (bi >> 1) & 1, ih = bi & 1;
  int tid = threadIdx.x;
  for(int idx = tid; idx < 1024; idx += 512)
    twl[idx >> 6][idx & 63] = TWX[(half*16 + (idx >> 6))*128 + (idx & 63)];
  __syncthreads();
  int i = ih*32 + (tid & 31), grp = (tid >> 5) & 3, mq = tid >> 7;
  const float2* yb = Y + ((size_t)(b*16 + ky)*128)*64 + i;
  float re[4] = {0,0,0,0}, im[4] = {0,0,0,0};
  for(int mi = 0; mi < 16; mi++){
    int mp = mq*16 + mi;
    float2 y1 = yb[(size_t)mp*64];
    float2 y2 = yb[(size_t)(mp + 64)*64];
    float2 ye = make_float2(y1.x + y2.x, y1.y + y2.y);
    float2 yo = make_float2(y1.x - y2.x, y1.y - y2.y);
    float2 t0 = twl[grp*4 + 0][mp];
    float2 t1 = twl[grp*4 + 1][mp];
    float2 t2 = twl[grp*4 + 2][mp];
    float2 t3 = twl[grp*4 + 3][mp];
    re[0] += ye.x*t0.x + ye.y*t0.y;  im[0] += ye.y*t0.x - ye.x*t0.y;
    re[1] += yo.x*t1.x + yo.y*t1.y;  im[1] += yo.y*t1.x - yo.x*t1.y;
    re[2] += ye.x*t2.x + ye.y*t2.y;  im[2] += ye.y*t2.x - ye.x*t2.y;
    re[3] += yo.x*t3.x + yo.y*t3.y;  im[3] += yo.y*t3.x - yo.x*t3.y;
  }
  if(mq){
    int sl = tid & 127;
    #pragma unroll
    for(int j = 0; j < 4; j++){ sc[mq-1][sl][j] = re[j]; sc[mq-1][sl][4 + j] = im[j]; }
  }
  __syncthreads();
  if(!mq){
    const float scn = 1.0f/128.0f;   // forward ortho norm (both axes)
    #pragma unroll
    for(int j = 0; j < 4; j++){
      float rr = (re[j] + sc[0][tid][j] + sc[1][tid][j] + sc[2][tid][j])*scn;
      float ii = (im[j] + sc[0][tid][4+j] + sc[1][tid][4+j] + sc[2][tid][4+j])*scn;
      int kp = half*16 + grp*4 + j;
      X2[((b*32 + kp)*16 + ky)*64 + i] = make_float2(rr, ii);
    }
  }
}

// ------- Stage 3: per-mode 64x64 complex mix, 2 p/block, 4-way i-split ------
__global__ __launch_bounds__(512) void k_mix(float2* __restrict__ X2,
                                             const float2* __restrict__ FWT){
  __shared__ float2 Xs[2][4][64];   // [pair_local][batch][i]
  __shared__ float sc[3][2][64][8];
  int tid = threadIdx.x;
  {
    int pl = tid >> 8, bq = (tid >> 6) & 3, ii = tid & 63;
    int p = blockIdx.x*2 + pl; int kp = p >> 4, kyy = p & 15;
    Xs[pl][bq][ii] = X2[((bq*32 + kp)*16 + kyy)*64 + ii];
  }
  __syncthreads();
  int o = tid & 63, w = tid >> 6, pl = w >> 2, iq = w & 3;
  int p = blockIdx.x*2 + pl; int kp = p >> 4, ky = p & 15;
  int arr = kp < 16 ? 0 : 1, kxw = kp < 16 ? kp : kp - 16;
  const float2* wp = FWT + ((size_t)((arr*16 + kxw)*16 + ky))*4096;
  float rr[4] = {0,0,0,0}, ii[4] = {0,0,0,0};
  for(int i = iq*16; i < iq*16 + 16; i++){
    float2 wv = wp[i*64 + o];
    #pragma unroll
    for(int b = 0; b < 4; b++){
      float xr = Xs[pl][b][i].x, xi = Xs[pl][b][i].y;
      rr[b] += xr*wv.x - xi*wv.y;
      ii[b] += xr*wv.y + xi*wv.x;
    }
  }
  if(iq){
    #pragma unroll
    for(int b = 0; b < 4; b++){ sc[iq-1][pl][o][b*2] = rr[b]; sc[iq-1][pl][o][b*2 + 1] = ii[b]; }
  }
  __syncthreads();
  if(!iq){
    #pragma unroll
    for(int b = 0; b < 4; b++){
      float r2 = rr[b] + sc[0][pl][o][b*2] + sc[1][pl][o][b*2] + sc[2][pl][o][b*2];
      float i2 = ii[b] + sc[0][pl][o][b*2+1] + sc[1][pl][o][b*2+1] + sc[2][pl][o][b*2+1];
      X2[((b*32 + kp)*16 + ky)*64 + o] = make_float2(r2, i2);
    }
  }
}

// ------- Stage 4 + GN1 stats: blocks [0,256) inv1 | [256,384) stat ----------
// inv1: inverse DFT over kx, radix-2 m, 2-way kp-split (as round 5).
// stat: GN1 group sums via Parseval directly on post-mix X2 (replaces k_cov +
// k_stat). Effective hermitian-extended spectrum bins:
//   ky>=1: weight 2 for all 32 kp.
//   ky=0 : kx=0 -> Re part only, weight 1; kx=j (j=1..15) pairs with
//          kx=128-j (kp=32-j): A=(X2[j]+conj(X2[32-j]))/2, weight 2;
//          kp=16 (kx=112, unpaired mirror kx=16 not kept): weight 1/2.
//   sa_n = 128*Re(X2[kp=0,ky=0])·w_n   (DC term).
__global__ __launch_bounds__(512) void k_inv1stat(const float2* __restrict__ OF,
                                                  const float2* __restrict__ TWX,
                                                  const short* __restrict__ W1g,
                                                  const float* __restrict__ PB,
                                                  float* __restrict__ ST,
                                                  float2* __restrict__ T){
  __shared__ __align__(16) char smu[36864];
  int bi = blockIdx.x;
  int tid = threadIdx.x;
  if(bi < 256){
    float2 (*Fl)[16]  = (float2(*)[16])smu;              // 4 KB
    float2 (*twl)[64] = (float2(*)[64])(smu + 4096);     // 16 KB
    float  (*sc)[16]  = (float(*)[16])(smu + 20480);     // 16 KB
    int b = bi >> 6, ky = (bi >> 2) & 15, oq = bi & 3;
    {
      int kp = tid >> 4, ol = tid & 15;
      Fl[kp][ol] = OF[((b*32 + kp)*16 + ky)*64 + oq*16 + ol];
    }
    for(int idx = tid; idx < 2048; idx += 512){
      int kp = idx >> 6, ml = idx & 63;
      twl[kp][ml] = TWX[kp*128 + ml];
    }
    __syncthreads();
    int ol = tid & 15, mg = (tid >> 4) & 15, kh = tid >> 8;
    float reE[4] = {0,0,0,0}, imE[4] = {0,0,0,0};
    float reO[4] = {0,0,0,0}, imO[4] = {0,0,0,0};
    for(int ip = 0; ip < 8; ip++){
      int kp = kh*16 + ip*2;
      float2 fe = Fl[kp][ol], fo = Fl[kp + 1][ol];
      #pragma unroll
      for(int u = 0; u < 4; u++){
        float2 te = twl[kp][mg*4 + u], to = twl[kp + 1][mg*4 + u];
        reE[u] += fe.x*te.x - fe.y*te.y;
        imE[u] += fe.x*te.y + fe.y*te.x;
        reO[u] += fo.x*to.x - fo.y*to.y;
        imO[u] += fo.x*to.y + fo.y*to.x;
      }
    }
    if(kh){
      int sl = tid & 255;
      #pragma unroll
      for(int u = 0; u < 4; u++){
        sc[sl][u] = reE[u]; sc[sl][4 + u] = imE[u];
        sc[sl][8 + u] = reO[u]; sc[sl][12 + u] = imO[u];
      }
    }
    __syncthreads();
    if(!kh){
      int o = oq*16 + ol;
      #pragma unroll
      for(int u = 0; u < 4; u++){
        float rE = reE[u] + sc[tid][u],     iE = imE[u] + sc[tid][4 + u];
        float rO = reO[u] + sc[tid][8 + u], iO = imO[u] + sc[tid][12 + u];
        int ml = mg*4 + u;
        T[((b*128 + ml)*16 + ky)*64 + o]      = make_float2(rE + rO, iE + iO);
        T[((b*128 + ml + 64)*16 + ky)*64 + o] = make_float2(rE - rO, iE - iO);
      }
    }
    return;
  }
  // ---------------- stat part ----------------
  {
    float2 (*Xs2)[34] = (float2(*)[34])smu;              // 64x34x8 = 17408 B
    float  (*Wl)[64]  = (float(*)[64])(smu + 17408);     // 4096 B
    float* g2 = (float*)(smu + 21504);                   // 8 B
    int sb = bi - 256;
    int br = sb >> 6, b = (sb >> 4) & 3, g = sb & 15;
    const short* W1 = W1g + br*16384;
    for(int u = tid; u < 1024; u += 512){
      int nl2 = u >> 6, k = u & 63;
      int n = g*16 + nl2;
      int fid = ((n >> 6)*4 + ((n >> 4) & 3))*2 + (k >> 5);
      int lane2 = ((k >> 3) & 3)*16 + (n & 15);
      Wl[nl2][k] = s2f(W1[fid*512 + lane2*8 + (k & 7)]);
    }
    if(tid < 2) g2[tid] = 0.f;
    int nl = tid >> 5, kp = tid & 31;
    int lane = tid & 63;
    float qa = 0.f, re0 = 0.f;
    for(int ky = 0; ky < 16; ky++){
      __syncthreads();
      {
        int skp = tid >> 4, i0 = (tid & 15)*4;
        const float2* src = OF + ((size_t)(b*32 + skp)*16 + ky)*64 + i0;
        #pragma unroll
        for(int j2 = 0; j2 < 4; j2++) Xs2[i0 + j2][skp] = src[j2];
      }
      __syncthreads();
      float re = 0.f, im = 0.f;
      const float* wr = Wl[nl];
      #pragma unroll 8
      for(int i = 0; i < 64; i++){
        float2 v = Xs2[i][kp];
        re += v.x*wr[i]; im += v.y*wr[i];
      }
      if(ky){
        qa += 2.f*(re*re + im*im);
      } else {
        int pl = (lane & 32) | ((32 - kp) & 31);
        float pre = __shfl(re, pl);
        float pim = __shfl(im, pl);
        if(kp == 0){ re0 = re; qa += re*re; }
        else if(kp == 16){ qa += 0.5f*(re*re + im*im); }
        else if(kp < 16){
          float ar = 0.5f*(re + pre), ai = 0.5f*(im - pim);
          qa += 2.f*(ar*ar + ai*ai);
        }
      }
    }
    for(int off = 16; off; off >>= 1) qa += __shfl_xor(qa, off);
    if(kp == 0){
      float sa = 128.f*re0;
      float bn = PB[br*2048 + g*16 + nl];
      float hs = sa + 16384.f*bn;
      float hq = qa + 2.f*bn*sa + 16384.f*bn*bn;
      atomicAdd(&g2[0], hs); atomicAdd(&g2[1], hq);
    }
    __syncthreads();
    if(tid == 0){
      float* S1 = ST + br*192;
      S1[(b*16 + g)*2]     = g2[0];
      S1[(b*16 + g)*2 + 1] = g2[1];
    }
  }
}

// ---------- Stage 5: hermitian C2R over ky, radix-2 over n, 512 blocks ------
__global__ __launch_bounds__(256) void k_inv2(const float2* __restrict__ T,
                                              const float2* __restrict__ TWY,
                                              bf16* __restrict__ XO){
  __shared__ float2 twl[16][64];
  int bi = blockIdx.x;
  int b = bi >> 7, m = bi & 127;
  int tid = threadIdx.x;
  for(int idx = tid; idx < 1024; idx += 256)
    twl[idx >> 6][idx & 63] = TWY[(idx >> 6)*128 + (idx & 63)];
  int o = tid & 63, ng = tid >> 6;
  const float2* tp = T + ((size_t)(b*128 + m)*16)*64 + o;
  float t0a = tp[0].x;
  float ax[15], ay[15];
  #pragma unroll
  for(int u = 0; u < 15; u++){
    float2 v = tp[(u + 1)*64];
    ax[u] = 2.f*v.x; ay[u] = 2.f*v.y;
  }
  __syncthreads();
  const float scn = 1.0f/128.0f;   // inverse ortho norm (both axes)
  bf16* xo = XO + ((size_t)(b*128 + m)*128)*64 + o;
  for(int np = ng*16; np < ng*16 + 16; np++){
    float A = t0a, B = 0.f;
    #pragma unroll
    for(int u = 0; u < 15; u++){   // ky = u+1; even ky <=> odd u
      float2 t = twl[u + 1][np];
      float pr = ax[u]*t.x - ay[u]*t.y;
      if(u & 1) A += pr; else B += pr;
    }
    xo[(size_t)np*64]        = __float2bfloat16((A + B)*scn);
    xo[(size_t)(np + 64)*64] = __float2bfloat16((A - B)*scn);
  }
}

// ------- FF main: GEMM1+GN1+relu+GEMM2 -> h2 bf16 + per-channel sums --------
// Stats (Sh,Sh2,Sz,Sz2,Shz) accumulated in fp32 BEFORE the bf16 rounding.
__global__ __launch_bounds__(256, 2) void k_ffmain(const bf16* __restrict__ XO,
                                                   const short* __restrict__ W1g,
                                                   const short* __restrict__ W2g,
                                                   const float* __restrict__ PB,
                                                   const float* __restrict__ ST,
                                                   const float* __restrict__ z,
                                                   float* __restrict__ CS,
                                                   unsigned short* __restrict__ H2){
  __shared__ short Ws1[16384];     // 32KB frag-order W1
  __shared__ short Ws2[16384];     // 32KB frag-order W2
  __shared__ short Hn[64][72];     // per-wave-private row slices
  __shared__ float mu1[16], rs1[16];
  __shared__ float cs[5][64];      // per-channel partial sums
  int tid = threadIdx.x;
  int br = blockIdx.x >> 8, rb = blockIdx.x & 255;
  int r0 = rb << 8, b = rb >> 6;
  const float* pb = PB + br*2048;
  int lane = tid & 63, w = tid >> 6, l15 = lane & 15, quad = lane >> 4;
  int myrow = w*16 + l15;
  short8 a0r[4], a1r[4];
  #pragma unroll
  for(int c = 0; c < 4; c++){
    const short* xop = (const short*)XO + ((size_t)(r0 + c*64 + myrow))*64;
    a0r[c] = *(const short8*)(xop + quad*8);
    a1r[c] = *(const short8*)(xop + 32 + quad*8);
  }
  {
    const uint4* g1 = (const uint4*)(W1g + br*16384);
    const uint4* g2w = (const uint4*)(W2g + br*16384);
    uint4* s1 = (uint4*)Ws1; uint4* s2 = (uint4*)Ws2;
    #pragma unroll
    for(int u = 0; u < 8; u++){
      s1[u*256 + tid] = g1[u*256 + tid];
      s2[u*256 + tid] = g2w[u*256 + tid];
    }
  }
  if(tid < 16){
    const float cnt = 262144.f;  // 128*128*16
    const float* S1 = ST + br*192;
    float s = S1[(b*16 + tid)*2], q = S1[(b*16 + tid)*2 + 1];
    float mean = s/cnt, var = q/cnt - mean*mean;
    mu1[tid] = mean; rs1[tid] = rsqrtf(fmaxf(var, 0.f) + EPSV);
  }
  {
    float* c1 = &cs[0][0];
    c1[tid] = 0.f;
    if(tid < 64) c1[256 + tid] = 0.f;
  }
  __syncthreads();
  float sh[4]  = {0,0,0,0}, sh2[4] = {0,0,0,0};
  float sz[4]  = {0,0,0,0}, sz2[4] = {0,0,0,0}, shz[4] = {0,0,0,0};
  #pragma unroll
  for(int c = 0; c < 4; c++){
    size_t obase_off = ((size_t)(b*2 + br)*16384 + (r0 & 16383) + c*64)*64;
    const float* zbase = z + obase_off;
    float zr[16];
    #pragma unroll
    for(int t = 0; t < 4; t++)
      #pragma unroll
      for(int r = 0; r < 4; r++)
        zr[t*4 + r] = zbase[(size_t)(w*16 + quad*4 + r)*64 + t*16 + l15];
    f32x4 acc2[4];
    #pragma unroll
    for(int t = 0; t < 4; t++) acc2[t] = (f32x4){0.f,0.f,0.f,0.f};
    for(int ch = 0; ch < 4; ch++){
      #pragma unroll
      for(int t = 0; t < 4; t++){
        int fid = (ch*4 + t)*2;
        short8 b0 = *(const short8*)(Ws1 + fid*512 + lane*8);
        short8 b1 = *(const short8*)(Ws1 + fid*512 + 512 + lane*8);
        f32x4 acc = {0.f,0.f,0.f,0.f};
        acc = __builtin_amdgcn_mfma_f32_16x16x32_bf16(a0r[c], b0, acc, 0, 0, 0);
        acc = __builtin_amdgcn_mfma_f32_16x16x32_bf16(a1r[c], b1, acc, 0, 0, 0);
        int n = ch*64 + t*16 + l15, gi = n >> 4;
        float w1v = pb[256 + n];
        float gwv = w1v * rs1[gi];
        float gbv = (pb[n] - mu1[gi])*rs1[gi]*w1v + pb[512 + n];
        #pragma unroll
        for(int r = 0; r < 4; r++){
          float hv = acc[r]*gwv + gbv;
          hv = hv > 0.f ? hv : 0.f;
          Hn[w*16 + quad*4 + r][t*16 + l15] = f2bs(hv);
        }
      }
      short8 ha0 = *(short8*)&Hn[myrow][quad*8];
      short8 ha1 = *(short8*)&Hn[myrow][32 + quad*8];
      #pragma unroll
      for(int t = 0; t < 4; t++){
        int fid = (ch*4 + t)*2;
        short8 b0 = *(const short8*)(Ws2 + fid*512 + lane*8);
        short8 b1 = *(const short8*)(Ws2 + fid*512 + 512 + lane*8);
        acc2[t] = __builtin_amdgcn_mfma_f32_16x16x32_bf16(ha0, b0, acc2[t], 0, 0, 0);
        acc2[t] = __builtin_amdgcn_mfma_f32_16x16x32_bf16(ha1, b1, acc2[t], 0, 0, 0);
      }
    }
    unsigned short* hbase = H2 + obase_off;
    #pragma unroll
    for(int t = 0; t < 4; t++){
      int col = t*16 + l15;
      float bias2 = pb[768 + col];
      #pragma unroll
      for(int r = 0; r < 4; r++){
        size_t off = (size_t)(w*16 + quad*4 + r)*64 + col;
        float h2 = acc2[t][r] + bias2;
        float zv = zr[t*4 + r];
        hbase[off] = (unsigned short)f2bs(h2);
        sh[t] += h2; sh2[t] += h2*h2;
        sz[t] += zv; sz2[t] += zv*zv; shz[t] += h2*zv;
      }
    }
  }
  #pragma unroll
  for(int t = 0; t < 4; t++){
    float v0 = sh[t], v1 = sh2[t], v2 = sz[t], v3 = sz2[t], v4 = shz[t];
    v0 += __shfl_xor(v0, 16); v0 += __shfl_xor(v0, 32);
    v1 += __shfl_xor(v1, 16); v1 += __shfl_xor(v1, 32);
    v2 += __shfl_xor(v2, 16); v2 += __shfl_xor(v2, 32);
    v3 += __shfl_xor(v3, 16); v3 += __shfl_xor(v3, 32);
    v4 += __shfl_xor(v4, 16); v4 += __shfl_xor(v4, 32);
    if(quad == 0){
      int ch = t*16 + l15;
      atomicAdd(&cs[0][ch], v0); atomicAdd(&cs[1][ch], v1);
      atomicAdd(&cs[2][ch], v2); atomicAdd(&cs[3][ch], v3);
      atomicAdd(&cs[4][ch], v4);
    }
  }
  __syncthreads();
  float* slab = CS + (size_t)blockIdx.x*320;
  const float* c1 = &cs[0][0];
  slab[tid] = c1[tid];
  if(tid < 64) slab[256 + tid] = c1[256 + tid];
}

// ------- StatB: GN2 params + analytic GN3 stats -> fused affine coeffs ------
__global__ __launch_bounds__(256) void k_statB(const float* __restrict__ CS,
                                               const float* __restrict__ PB,
                                               float* __restrict__ CF){
  __shared__ float chs[5][64];
  __shared__ float mu2s[4], rs2s[4], tg[4], tq[4], mu3s[4], rs3s[4];
  int br = blockIdx.x >> 2, b = blockIdx.x & 3;
  int tid = threadIdx.x;
  const float* base = CS + ((size_t)(br*256 + b*64))*320;
  float* c1 = &chs[0][0];
  for(int v = tid; v < 320; v += 256){
    float s = 0.f;
    for(int k = 0; k < 64; k++) s += base[(size_t)k*320 + v];
    c1[v] = s;
  }
  __syncthreads();
  if(tid < 4){
    float s = 0.f, q = 0.f;
    for(int o = tid*16; o < tid*16 + 16; o++){ s += chs[0][o]; q += chs[1][o]; }
    float mean = s/262144.f, var = q/262144.f - mean*mean;
    mu2s[tid] = mean; rs2s[tid] = rsqrtf(fmaxf(var, 0.f) + EPSV);
    tg[tid] = 0.f; tq[tid] = 0.f;
  }
  __syncthreads();
  const float* pb = PB + br*2048;
  if(tid < 64){
    int o = tid, g = o >> 4;
    float w2v = pb[832 + o], b2v = pb[896 + o];
    float gw = w2v*rs2s[g], gb = b2v - mu2s[g]*rs2s[g]*w2v;
    float Sh = chs[0][o], Sh2 = chs[1][o], Sz = chs[2][o], Sz2 = chs[3][o], Shz = chs[4][o];
    float st = gw*Sh + Sz + 16384.f*gb;
    float sq = gw*gw*Sh2 + Sz2 + 16384.f*gb*gb + 2.f*gw*Shz + 2.f*gw*gb*Sh + 2.f*gb*Sz;
    atomicAdd(&tg[g], st); atomicAdd(&tq[g], sq);
  }
  __syncthreads();
  if(tid < 4){
    float mean = tg[tid]/262144.f, var = tq[tid]/262144.f - mean*mean;
    mu3s[tid] = mean; rs3s[tid] = rsqrtf(fmaxf(var, 0.f) + EPSV);
  }
  __syncthreads();
  if(tid < 64){
    int o = tid, g = o >> 4;
    float w2v = pb[832 + o], b2v = pb[896 + o];
    float gw = w2v*rs2s[g], gb = b2v - mu2s[g]*rs2s[g]*w2v;
    float w3v = pb[960 + o], b3v = pb[1024 + o];
    float gw3 = w3v*rs3s[g], gb3 = b3v - mu3s[g]*rs3s[g]*w3v;
    float* cf = CF + (size_t)(br*4 + b)*192;
    cf[o]       = gw*gw3;          // alpha (h2 coefficient)
    cf[64 + o]  = gw3;             // beta  (z coefficient)
    cf[128 + o] = gb*gw3 + gb3;    // gamma
  }
}

// ------- Final: out = alpha*h2(bf16) + beta*z + gamma ------------------------
__global__ __launch_bounds__(256) void k_final(const float* __restrict__ z,
                                               const float* __restrict__ CF,
                                               const unsigned short* __restrict__ H2,
                                               float* __restrict__ out){
  int tid = blockIdx.x*256 + threadIdx.x;
  const float4* z4 = (const float4*)z;
  const float4* cf4 = (const float4*)CF;
  const ushort4* h4 = (const ushort4*)H2;
  float4* o4 = (float4*)out;
  #pragma unroll
  for(int r = 0; r < 8; r++){
    int i4 = r*262144 + tid;
    int s = i4 >> 18;                 // (b*2+br)
    int b = s >> 1, br = s & 1;
    int cbase = (br*4 + b)*48 + (i4 & 15);
    float4 a = cf4[cbase], bb = cf4[cbase + 16], g = cf4[cbase + 32];
    ushort4 hu = h4[i4];
    float4 zv = z4[i4];
    o4[i4] = make_float4(s2f((short)hu.x)*a.x + zv.x*bb.x + g.x,
                         s2f((short)hu.y)*a.y + zv.y*bb.y + g.y,
                         s2f((short)hu.z)*a.z + zv.z*bb.z + g.z,
                         s2f((short)hu.w)*a.w + zv.w*bb.w + g.w);
  }
}

extern "C" void kernel_launch(void* const* d_in, const int* in_sizes, int n_in,
                              void* d_out, int out_size, void* d_ws, size_t ws_size,
                              hipStream_t stream){
  const float* z   = (const float*)d_in[0];
  const float* x   = (const float*)d_in[1];
  const float* fw1 = (const float*)d_in[2];
  const float* fw2 = (const float*)d_in[3];
  char* ws = (char*)d_ws;
  // workspace layout (byte offsets)
  float2* Y   = (float2*)(ws + 0);           // 4,194,304 B  [b][ky][m][i]
  float2* X2  = (float2*)(ws + 4194304);     // 1,048,576 B
  float2* T   = Y;                           // alias: Y dead after k_xdft
  bf16*   XO  = (bf16*)(ws + 5242880);       // 8,388,608 B
  float*  ST  = (float*)(ws + 13631488);     // 2,048 B
  short*  W1g = (short*)(ws + 13633536);     // 65,536 B
  short*  W2g = (short*)(ws + 13699072);     // 65,536 B
  float2* TWY = (float2*)(ws + 13764608);    // 16,384 B
  float2* TWX = (float2*)(ws + 13780992);    // 32,768 B
  float*  PB  = (float*)(ws + 13813760);     // 16,384 B
  float2* FWT = (float2*)(ws + 13830144);    // 16,777,216 B -> ends 30,607,360
  // Aliases into the FWT region (FWT dead after k_mix):
  float*  CS  = (float*)(ws + 14878720);     // 655,360 B (512 slabs x 320)
  float*  CF  = (float*)(ws + 15927296);     // 6,144 B   (8 x 192)
  unsigned short* H2 = (unsigned short*)(ws + 16777216);  // 16,777,216 B bf16 h2

  const float* p[20];
  for(int i = 0; i < 20; i++) p[i] = (const float*)d_in[4 + i];

  k_prep_ydft<<<1314, 256, 0, stream>>>(x, z, fw1, fw2, FWT,
                                  p[0],p[1],p[2],p[3],p[4],p[5],p[6],p[7],p[8],p[9],
                                  p[10],p[11],p[12],p[13],p[14],p[15],p[16],p[17],p[18],p[19],
                                  W1g, W2g, TWY, TWX, PB, ST, Y);
  k_xdft<<<256, 512, 0, stream>>>(Y, TWX, X2);
  k_mix<<<256, 512, 0, stream>>>(X2, FWT);
  k_inv1stat<<<384, 512, 0, stream>>>(X2, TWX, W1g, PB, ST, T);
  k_inv2<<<512, 256, 0, stream>>>(T, TWY, XO);
  k_ffmain<<<512, 256, 0, stream>>>(XO, W1g, W2g, PB, ST, z, CS, H2);
  k_statB<<<8, 256, 0, stream>>>(CS, PB, CF);
  k_final<<<1024, 256, 0, stream>>>(z, CF, H2, (float*)d_out);
}

// Round 7
// 240.541 us; speedup vs baseline: 1.0597x; 1.0597x over previous
//
#include <hip/hip_runtime.h>
#include <hip/hip_bf16.h>

typedef __hip_bfloat16 bf16;
typedef __attribute__((ext_vector_type(8))) short short8;   // 8 bf16 (4 VGPRs)
typedef __attribute__((ext_vector_type(4))) float f32x4;    // 4 fp32 acc

#define PI2 6.283185307179586f
#define EPSV 1e-5f

__device__ __forceinline__ short f2bs(float f){
  bf16 h = __float2bfloat16(f);
  short s; __builtin_memcpy(&s, &h, 2); return s;
}
__device__ __forceinline__ float s2f(short s){
  bf16 h; __builtin_memcpy(&h, &s, 2); return __bfloat162float(h);
}
__device__ __forceinline__ float4 f4add(float4 a, float4 b){ return make_float4(a.x+b.x, a.y+b.y, a.z+b.z, a.w+b.w); }
__device__ __forceinline__ float4 f4sub(float4 a, float4 b){ return make_float4(a.x-b.x, a.y-b.y, a.z-b.z, a.w-b.w); }

// ------ Prep+ydft merged: blocks [0,512) ydft | [512,1024) FWT | rest misc ---
__global__ __launch_bounds__(256) void k_prep_ydft(
    const float* __restrict__ x, const float* __restrict__ z,
    const float* __restrict__ fw1, const float* __restrict__ fw2,
    float2* __restrict__ FWT,
    const float* __restrict__ b_l1w, const float* __restrict__ b_l1b,
    const float* __restrict__ b_l2w, const float* __restrict__ b_l2b,
    const float* __restrict__ b_g1w, const float* __restrict__ b_g1b,
    const float* __restrict__ b_g2w, const float* __restrict__ b_g2b,
    const float* __restrict__ b_g3w, const float* __restrict__ b_g3b,
    const float* __restrict__ f_l1w, const float* __restrict__ f_l1b,
    const float* __restrict__ f_l2w, const float* __restrict__ f_l2b,
    const float* __restrict__ f_g1w, const float* __restrict__ f_g1b,
    const float* __restrict__ f_g2w, const float* __restrict__ f_g2b,
    const float* __restrict__ f_g3w, const float* __restrict__ f_g3b,
    short* __restrict__ W1g, short* __restrict__ W2g,
    float2* __restrict__ TWY, float2* __restrict__ TWX,
    float* __restrict__ PB, float* __restrict__ ST,
    float2* __restrict__ Y){
  __shared__ __align__(16) char sm[36864];
  int tid = threadIdx.x;
  int bi = blockIdx.x;
  if(bi < 512){
    float2 (*PQ)[64] = (float2(*)[64])sm;              // 16KB
    float2 (*RS)[64] = (float2(*)[64])(sm + 16384);    // 16KB
    float4 (*twl)[32] = (float4(*)[32])(sm + 32768);   // 4KB [kq2][np], kq2<8
    int b = bi >> 7, m = bi & 127;
    const float4* xp = (const float4*)(x + ((size_t)(b*128 + m)*128)*64);
    const float4* zp = (const float4*)(z + ((size_t)((b*2 + 0)*128 + m)*128)*64);
    int i4 = tid & 15, n0 = tid >> 4;
    #pragma unroll
    for(int it = 0; it < 2; it++){
      int np = n0 + it*16;
      float4 ea = f4sub(xp[np*16 + i4],      zp[np*16 + i4]);
      float4 eb = f4sub(xp[(np+32)*16 + i4], zp[(np+32)*16 + i4]);
      float4 ec = f4sub(xp[(np+64)*16 + i4], zp[(np+64)*16 + i4]);
      float4 ed = f4sub(xp[(np+96)*16 + i4], zp[(np+96)*16 + i4]);
      float4 sac = f4add(ea, ec), sbd = f4add(eb, ed);
      float4 P = f4add(sac, sbd), Q = f4sub(sac, sbd);
      float4 R = f4sub(ea, ec),  S = f4sub(eb, ed);
      *(float4*)&PQ[np][i4*4]     = make_float4(P.x, Q.x, P.y, Q.y);
      *(float4*)&PQ[np][i4*4 + 2] = make_float4(P.z, Q.z, P.w, Q.w);
      *(float4*)&RS[np][i4*4]     = make_float4(R.x, S.x, R.y, S.y);
      *(float4*)&RS[np][i4*4 + 2] = make_float4(R.z, S.z, R.w, S.w);
    }
    {
      int kq2 = tid >> 5, np = tid & 31;          // kq2 in [0,8)
      int ky0 = (kq2 >> 1)*4 + (kq2 & 1)*2;
      float s0, c0, s1, c1;
      sincosf(PI2*(float)((ky0*np) & 127)/128.f, &s0, &c0);
      sincosf(PI2*(float)(((ky0+1)*np) & 127)/128.f, &s1, &c1);
      twl[kq2][np] = make_float4(c0, s0, c1, s1);
    }
    __syncthreads();
    int i = tid & 63, kq = tid >> 6;
    float re[4] = {0,0,0,0}, im[4] = {0,0,0,0};
    for(int np = 0; np < 32; np++){
      float2 pq = PQ[np][i];
      float2 rs = RS[np][i];
      float4 t01 = twl[kq*2][np];
      float4 t23 = twl[kq*2 + 1][np];
      re[0] += pq.x*t01.x;               im[0] -= pq.x*t01.y;
      re[1] += rs.x*t01.z - rs.y*t01.w;  im[1] -= rs.y*t01.z + rs.x*t01.w;
      re[2] += pq.y*t23.x;               im[2] -= pq.y*t23.y;
      re[3] += rs.x*t23.z + rs.y*t23.w;  im[3] += rs.y*t23.z - rs.x*t23.w;
    }
    #pragma unroll
    for(int j = 0; j < 4; j++)
      Y[(((size_t)b*16 + kq*4 + j)*128 + m)*64 + i] = make_float2(re[j], im[j]);
    return;
  }
  if(bi < 1024){
    float (*Ls)[512] = (float(*)[512])sm;   // 32KB
    int bb = bi - 512;
    int arr = bb >> 8, rem = bb & 255;
    int i = rem >> 2, o0 = (rem & 3) * 16;
    const float* src = (arr ? fw2 : fw1) + ((size_t)(i*64 + o0))*512;
    for(int idx = tid; idx < 8192; idx += 256)
      Ls[idx >> 9][idx & 511] = src[idx];
    __syncthreads();
    int kxw = tid >> 4, ky = tid & 15;
    float2* dst = FWT + ((size_t)((arr*16 + kxw)*16 + ky))*4096 + i*64 + o0;
    for(int ol = 0; ol < 16; ol++)
      dst[ol] = make_float2(Ls[ol][tid*2], Ls[ol][tid*2 + 1]);
    return;
  }
  int i = (bi - 1024)*256 + tid;
  if(i < 32768){                         // W1g fragment layout
    int br = i >> 14, r = i & 16383;
    int fid = r >> 9, lane = (r >> 3) & 63, e = r & 7;
    int hb = fid & 1, t = (fid >> 1) & 3, ch = fid >> 3;
    int l15 = lane & 15, quad = lane >> 4;
    int n = ch*64 + t*16 + l15;
    int k = hb*32 + quad*8 + e;
    const float* src = br ? f_l1w : b_l1w;
    W1g[i] = f2bs(src[k*256 + n]);
    return;
  }
  i -= 32768;
  if(i < 32768){                         // W2g fragment layout
    int br = i >> 14, r = i & 16383;
    int fid = r >> 9, lane = (r >> 3) & 63, e = r & 7;
    int hb = fid & 1, t = (fid >> 1) & 3, ch = fid >> 3;
    int l15 = lane & 15, quad = lane >> 4;
    int n = t*16 + l15;
    int k = ch*64 + hb*32 + quad*8 + e;
    const float* src = br ? f_l2w : b_l2w;
    W2g[i] = f2bs(src[k*64 + n]);
    return;
  }
  i -= 32768;
  if(i < 2048){                          // TWY[ky][n]
    int ky = i >> 7, n = i & 127;
    float ang = PI2 * (float)((ky*n) & 127) / 128.0f;
    float s, c; sincosf(ang, &s, &c);
    TWY[i] = make_float2(c, s);
    return;
  }
  i -= 2048;
  if(i < 4096){                          // TWX[kp][m]
    int kp = i >> 7, m = i & 127;
    int kx = kp < 16 ? kp : 96 + kp;
    float ang = PI2 * (float)((kx*m) & 127) / 128.0f;
    float s, c; sincosf(ang, &s, &c);
    TWX[i] = make_float2(c, s);
    return;
  }
  i -= 4096;
  if(i < 384){ ST[i] = 0.f; return; }    // zero stats
  i -= 384;
  if(i < 2176){                          // param block
    int br = i >= 1088; int o = i - br*1088;
    float* pb = PB + br*2048;
    float v;
    if(o < 256)       v = (br ? f_l1b : b_l1b)[o];
    else if(o < 512)  v = (br ? f_g1w : b_g1w)[o-256];
    else if(o < 768)  v = (br ? f_g1b : b_g1b)[o-512];
    else if(o < 832)  v = (br ? f_l2b : b_l2b)[o-768];
    else if(o < 896)  v = (br ? f_g2w : b_g2w)[o-832];
    else if(o < 960)  v = (br ? f_g2b : b_g2b)[o-896];
    else if(o < 1024) v = (br ? f_g3w : b_g3w)[o-960];
    else              v = (br ? f_g3b : b_g3b)[o-1024];
    pb[o] = v;
  }
}

// ------- Stage 2: DFT over x, radix-2 over m, 4-way m-split, 512 thr --------
// Also zeroes Cg (fresh region; k_mix still reads FWT so no aliasing).
__global__ __launch_bounds__(512) void k_xdft(const float2* __restrict__ Y,
                                              const float2* __restrict__ TWX,
                                              float2* __restrict__ X2,
                                              float* __restrict__ CgZ){
  __shared__ float2 twl[16][64];
  __shared__ float sc[3][128][8];
  int bi = blockIdx.x;
  int b = bi >> 6, ky = (bi >> 2) & 15, half = (bi >> 1) & 1, ih = bi & 1;
  int tid = threadIdx.x;
  int flat = bi*512 + tid;
  if(flat < 16384) CgZ[flat] = 0.f;
  for(int idx = tid; idx < 1024; idx += 512)
    twl[idx >> 6][idx & 63] = TWX[(half*16 + (idx >> 6))*128 + (idx & 63)];
  __syncthreads();
  int i = ih*32 + (tid & 31), grp = (tid >> 5) & 3, mq = tid >> 7;
  const float2* yb = Y + ((size_t)(b*16 + ky)*128)*64 + i;
  float re[4] = {0,0,0,0}, im[4] = {0,0,0,0};
  for(int mi = 0; mi < 16; mi++){
    int mp = mq*16 + mi;
    float2 y1 = yb[(size_t)mp*64];
    float2 y2 = yb[(size_t)(mp + 64)*64];
    float2 ye = make_float2(y1.x + y2.x, y1.y + y2.y);
    float2 yo = make_float2(y1.x - y2.x, y1.y - y2.y);
    float2 t0 = twl[grp*4 + 0][mp];
    float2 t1 = twl[grp*4 + 1][mp];
    float2 t2 = twl[grp*4 + 2][mp];
    float2 t3 = twl[grp*4 + 3][mp];
    re[0] += ye.x*t0.x + ye.y*t0.y;  im[0] += ye.y*t0.x - ye.x*t0.y;
    re[1] += yo.x*t1.x + yo.y*t1.y;  im[1] += yo.y*t1.x - yo.x*t1.y;
    re[2] += ye.x*t2.x + ye.y*t2.y;  im[2] += ye.y*t2.x - ye.x*t2.y;
    re[3] += yo.x*t3.x + yo.y*t3.y;  im[3] += yo.y*t3.x - yo.x*t3.y;
  }
  if(mq){
    int sl = tid & 127;
    #pragma unroll
    for(int j = 0; j < 4; j++){ sc[mq-1][sl][j] = re[j]; sc[mq-1][sl][4 + j] = im[j]; }
  }
  __syncthreads();
  if(!mq){
    const float scn = 1.0f/128.0f;   // forward ortho norm (both axes)
    #pragma unroll
    for(int j = 0; j < 4; j++){
      float rr = (re[j] + sc[0][tid][j] + sc[1][tid][j] + sc[2][tid][j])*scn;
      float ii = (im[j] + sc[0][tid][4+j] + sc[1][tid][4+j] + sc[2][tid][4+j])*scn;
      int kp = half*16 + grp*4 + j;
      X2[((b*32 + kp)*16 + ky)*64 + i] = make_float2(rr, ii);
    }
  }
}

// ------- Stage 3: per-mode 64x64 complex mix, 2 p/block, 4-way i-split ------
__global__ __launch_bounds__(512) void k_mix(float2* __restrict__ X2,
                                             const float2* __restrict__ FWT){
  __shared__ float2 Xs[2][4][64];   // [pair_local][batch][i]
  __shared__ float sc[3][2][64][8];
  int tid = threadIdx.x;
  {
    int pl = tid >> 8, bq = (tid >> 6) & 3, ii = tid & 63;
    int p = blockIdx.x*2 + pl; int kp = p >> 4, kyy = p & 15;
    Xs[pl][bq][ii] = X2[((bq*32 + kp)*16 + kyy)*64 + ii];
  }
  __syncthreads();
  int o = tid & 63, w = tid >> 6, pl = w >> 2, iq = w & 3;
  int p = blockIdx.x*2 + pl; int kp = p >> 4, ky = p & 15;
  int arr = kp < 16 ? 0 : 1, kxw = kp < 16 ? kp : kp - 16;
  const float2* wp = FWT + ((size_t)((arr*16 + kxw)*16 + ky))*4096;
  float rr[4] = {0,0,0,0}, ii[4] = {0,0,0,0};
  for(int i = iq*16; i < iq*16 + 16; i++){
    float2 wv = wp[i*64 + o];
    #pragma unroll
    for(int b = 0; b < 4; b++){
      float xr = Xs[pl][b][i].x, xi = Xs[pl][b][i].y;
      rr[b] += xr*wv.x - xi*wv.y;
      ii[b] += xr*wv.y + xi*wv.x;
    }
  }
  if(iq){
    #pragma unroll
    for(int b = 0; b < 4; b++){ sc[iq-1][pl][o][b*2] = rr[b]; sc[iq-1][pl][o][b*2 + 1] = ii[b]; }
  }
  __syncthreads();
  if(!iq){
    #pragma unroll
    for(int b = 0; b < 4; b++){
      float r2 = rr[b] + sc[0][pl][o][b*2] + sc[1][pl][o][b*2] + sc[2][pl][o][b*2];
      float i2 = ii[b] + sc[0][pl][o][b*2+1] + sc[1][pl][o][b*2+1] + sc[2][pl][o][b*2+1];
      X2[((b*32 + kp)*16 + ky)*64 + o] = make_float2(r2, i2);
    }
  }
}

// ------- Stage 4 + spectral cov: blocks [0,256) inv1 | [256,272) scov -------
// scov: S[b] += sum_bins w * (Re (x) Re + Im (x) Im) via bf16 MFMA over scaled
// rows (sqrt-weights); Parseval weights as verified in round 6:
//   ky>=1: w=2 ; ky=0: kp=0 Re-only w=1, kp 1..15 paired-avg w=2,
//   kp=16 w=1/2, kp 17..31 folded (zero rows).  SX[b][i] = 128*Re(X2[b,0,0,i]).
__global__ __launch_bounds__(512) void k_inv1scov(const float2* __restrict__ OF,
                                                  const float2* __restrict__ TWX,
                                                  float* __restrict__ Cg,
                                                  float* __restrict__ SX,
                                                  float2* __restrict__ T){
  __shared__ __align__(16) char smu[36864];
  int bi = blockIdx.x;
  int tid = threadIdx.x;
  if(bi < 256){
    float2 (*Fl)[16]  = (float2(*)[16])smu;              // 4 KB
    float2 (*twl)[64] = (float2(*)[64])(smu + 4096);     // 16 KB
    float  (*sc)[16]  = (float(*)[16])(smu + 20480);     // 16 KB
    int b = bi >> 6, ky = (bi >> 2) & 15, oq = bi & 3;
    {
      int kp = tid >> 4, ol = tid & 15;
      Fl[kp][ol] = OF[((b*32 + kp)*16 + ky)*64 + oq*16 + ol];
    }
    for(int idx = tid; idx < 2048; idx += 512){
      int kp = idx >> 6, ml = idx & 63;
      twl[kp][ml] = TWX[kp*128 + ml];
    }
    __syncthreads();
    int ol = tid & 15, mg = (tid >> 4) & 15, kh = tid >> 8;
    float reE[4] = {0,0,0,0}, imE[4] = {0,0,0,0};
    float reO[4] = {0,0,0,0}, imO[4] = {0,0,0,0};
    for(int ip = 0; ip < 8; ip++){
      int kp = kh*16 + ip*2;
      float2 fe = Fl[kp][ol], fo = Fl[kp + 1][ol];
      #pragma unroll
      for(int u = 0; u < 4; u++){
        float2 te = twl[kp][mg*4 + u], to = twl[kp + 1][mg*4 + u];
        reE[u] += fe.x*te.x - fe.y*te.y;
        imE[u] += fe.x*te.y + fe.y*te.x;
        reO[u] += fo.x*to.x - fo.y*to.y;
        imO[u] += fo.x*to.y + fo.y*to.x;
      }
    }
    if(kh){
      int sl = tid & 255;
      #pragma unroll
      for(int u = 0; u < 4; u++){
        sc[sl][u] = reE[u]; sc[sl][4 + u] = imE[u];
        sc[sl][8 + u] = reO[u]; sc[sl][12 + u] = imO[u];
      }
    }
    __syncthreads();
    if(!kh){
      int o = oq*16 + ol;
      #pragma unroll
      for(int u = 0; u < 4; u++){
        float rE = reE[u] + sc[tid][u],     iE = imE[u] + sc[tid][4 + u];
        float rO = reO[u] + sc[tid][8 + u], iO = imO[u] + sc[tid][12 + u];
        int ml = mg*4 + u;
        T[((b*128 + ml)*16 + ky)*64 + o]      = make_float2(rE + rO, iE + iO);
        T[((b*128 + ml + 64)*16 + ky)*64 + o] = make_float2(rE - rO, iE - iO);
      }
    }
    return;
  }
  // ---------------- scov wing: 16 blocks (b, quarter) ----------------
  {
    short (*XT)[264] = (short(*)[264])smu;   // 64 x 264 shorts = 33792 B
    int sb = bi - 256;
    int b = sb >> 2, q = sb & 3;
    const float RT2 = 1.41421356237f, RTH = 0.70710678118f;
    int c0 = (tid & 7)*8;
    #pragma unroll
    for(int it = 0; it < 4; it++){
      int pl = it*64 + (tid >> 3);           // row local in [0,256)
      int rg = q*256 + pl;
      int bin = rg >> 1, reim = rg & 1;
      int kp = bin >> 4, ky = bin & 15;
      const float2* base = OF + ((size_t)((b*32 + kp)*16 + ky))*64;
      #pragma unroll
      for(int e = 0; e < 8; e++){
        int i = c0 + e;
        float v;
        if(ky){
          float2 t = base[i];
          v = (reim ? t.y : t.x)*RT2;
        } else if(kp == 0){
          v = reim ? 0.f : base[i].x;
        } else if(kp < 16){
          const float2* mb = OF + ((size_t)((b*32 + (32 - kp))*16))*64;
          float2 t = base[i], u2 = mb[i];
          v = (reim ? 0.5f*(t.y - u2.y) : 0.5f*(t.x + u2.x))*RT2;
        } else if(kp == 16){
          float2 t = base[i];
          v = (reim ? t.y : t.x)*RTH;
        } else {
          v = 0.f;
        }
        XT[i][pl] = f2bs(v);
      }
    }
    if(q == 0 && tid < 64)
      SX[b*64 + tid] = 128.f * OF[((size_t)(b*32)*16)*64 + tid].x;
    __syncthreads();
    int lane = tid & 63, w8 = tid >> 6, wr = w8 & 3, kh = w8 >> 2;
    int l15 = lane & 15, quad = lane >> 4;
    f32x4 acc[4];
    #pragma unroll
    for(int tj = 0; tj < 4; tj++) acc[tj] = (f32x4){0.f,0.f,0.f,0.f};
    for(int kk = kh*4; kk < kh*4 + 4; kk++){
      short8 a = *(const short8*)&XT[wr*16 + l15][kk*32 + quad*8];
      #pragma unroll
      for(int tj = 0; tj < 4; tj++){
        short8 bfr = *(const short8*)&XT[tj*16 + l15][kk*32 + quad*8];
        acc[tj] = __builtin_amdgcn_mfma_f32_16x16x32_bf16(a, bfr, acc[tj], 0, 0, 0);
      }
    }
    float* Cb = Cg + b*4096;
    #pragma unroll
    for(int tj = 0; tj < 4; tj++)
      #pragma unroll
      for(int r = 0; r < 4; r++)
        atomicAdd(&Cb[(wr*16 + quad*4 + r)*64 + tj*16 + l15], acc[tj][r]);
  }
}

// ------- Stat: GN1 group sums from quadratic form; writes S1 directly -------
__global__ __launch_bounds__(256) void k_stat(const float* __restrict__ Cg,
                                              const float* __restrict__ SX,
                                              const short* __restrict__ W1g,
                                              const float* __restrict__ PB,
                                              float* __restrict__ ST){
  __shared__ float Cl[64][65];
  __shared__ float Wl[16][64];
  __shared__ float sxl[64];
  __shared__ float g2[2];
  int tid = threadIdx.x;
  int br = blockIdx.x >> 6, b = (blockIdx.x >> 4) & 3, g = blockIdx.x & 15;
  const float* Cb = Cg + b*4096;
  for(int u = tid; u < 4096; u += 256) Cl[u >> 6][u & 63] = Cb[u];
  const short* W1 = W1g + br*16384;
  for(int u = tid; u < 1024; u += 256){
    int nl = u >> 6, k = u & 63;
    int n = g*16 + nl;
    int fid = ((n >> 6)*4 + ((n >> 4) & 3))*2 + (k >> 5);
    int lane = ((k >> 3) & 3)*16 + (n & 15);
    Wl[nl][k] = s2f(W1[fid*512 + lane*8 + (k & 7)]);
  }
  if(tid < 64) sxl[tid] = SX[b*64 + tid];
  if(tid < 2) g2[tid] = 0.f;
  __syncthreads();
  int nl = tid >> 4, ic = tid & 15;
  float qa = 0.f, sa = 0.f;
  for(int io = 0; io < 4; io++){
    int i = ic*4 + io;
    float wi = Wl[nl][i];
    float dot = 0.f;
    #pragma unroll 8
    for(int j = 0; j < 64; j++) dot += Cl[i][j]*Wl[nl][j];
    qa += wi*dot;
    sa += wi*sxl[i];
  }
  for(int off = 8; off; off >>= 1){
    qa += __shfl_xor(qa, off);
    sa += __shfl_xor(sa, off);
  }
  if(ic == 0){
    float bn = PB[br*2048 + g*16 + nl];
    float hs = sa + 16384.f*bn;
    float hq = qa + 2.f*bn*sa + 16384.f*bn*bn;
    atomicAdd(&g2[0], hs); atomicAdd(&g2[1], hq);
  }
  __syncthreads();
  if(tid == 0){
    float* S1 = ST + br*192;
    S1[(b*16 + g)*2]     = g2[0];
    S1[(b*16 + g)*2 + 1] = g2[1];
  }
}

// ---------- Stage 5: hermitian C2R over ky, radix-2 over n, 512 blocks ------
__global__ __launch_bounds__(256) void k_inv2(const float2* __restrict__ T,
                                              const float2* __restrict__ TWY,
                                              bf16* __restrict__ XO){
  __shared__ float2 twl[16][64];
  int bi = blockIdx.x;
  int b = bi >> 7, m = bi & 127;
  int tid = threadIdx.x;
  for(int idx = tid; idx < 1024; idx += 256)
    twl[idx >> 6][idx & 63] = TWY[(idx >> 6)*128 + (idx & 63)];
  int o = tid & 63, ng = tid >> 6;
  const float2* tp = T + ((size_t)(b*128 + m)*16)*64 + o;
  float t0a = tp[0].x;
  float ax[15], ay[15];
  #pragma unroll
  for(int u = 0; u < 15; u++){
    float2 v = tp[(u + 1)*64];
    ax[u] = 2.f*v.x; ay[u] = 2.f*v.y;
  }
  __syncthreads();
  const float scn = 1.0f/128.0f;   // inverse ortho norm (both axes)
  bf16* xo = XO + ((size_t)(b*128 + m)*128)*64 + o;
  for(int np = ng*16; np < ng*16 + 16; np++){
    float A = t0a, B = 0.f;
    #pragma unroll
    for(int u = 0; u < 15; u++){   // ky = u+1; even ky <=> odd u
      float2 t = twl[u + 1][np];
      float pr = ax[u]*t.x - ay[u]*t.y;
      if(u & 1) A += pr; else B += pr;
    }
    xo[(size_t)np*64]        = __float2bfloat16((A + B)*scn);
    xo[(size_t)(np + 64)*64] = __float2bfloat16((A - B)*scn);
  }
}

// ------- FF main: GEMM1+GN1+relu+GEMM2 -> h2 bf16 + per-channel sums --------
__global__ __launch_bounds__(256, 2) void k_ffmain(const bf16* __restrict__ XO,
                                                   const short* __restrict__ W1g,
                                                   const short* __restrict__ W2g,
                                                   const float* __restrict__ PB,
                                                   const float* __restrict__ ST,
                                                   const float* __restrict__ z,
                                                   float* __restrict__ CS,
                                                   unsigned short* __restrict__ H2){
  __shared__ short Ws1[16384];     // 32KB frag-order W1
  __shared__ short Ws2[16384];     // 32KB frag-order W2
  __shared__ short Hn[64][72];     // per-wave-private row slices
  __shared__ float mu1[16], rs1[16];
  __shared__ float cs[5][64];      // per-channel partial sums
  int tid = threadIdx.x;
  int br = blockIdx.x >> 8, rb = blockIdx.x & 255;
  int r0 = rb << 8, b = rb >> 6;
  const float* pb = PB + br*2048;
  int lane = tid & 63, w = tid >> 6, l15 = lane & 15, quad = lane >> 4;
  int myrow = w*16 + l15;
  short8 a0r[4], a1r[4];
  #pragma unroll
  for(int c = 0; c < 4; c++){
    const short* xop = (const short*)XO + ((size_t)(r0 + c*64 + myrow))*64;
    a0r[c] = *(const short8*)(xop + quad*8);
    a1r[c] = *(const short8*)(xop + 32 + quad*8);
  }
  {
    const uint4* g1 = (const uint4*)(W1g + br*16384);
    const uint4* g2w = (const uint4*)(W2g + br*16384);
    uint4* s1 = (uint4*)Ws1; uint4* s2 = (uint4*)Ws2;
    #pragma unroll
    for(int u = 0; u < 8; u++){
      s1[u*256 + tid] = g1[u*256 + tid];
      s2[u*256 + tid] = g2w[u*256 + tid];
    }
  }
  if(tid < 16){
    const float cnt = 262144.f;  // 128*128*16
    const float* S1 = ST + br*192;
    float s = S1[(b*16 + tid)*2], q = S1[(b*16 + tid)*2 + 1];
    float mean = s/cnt, var = q/cnt - mean*mean;
    mu1[tid] = mean; rs1[tid] = rsqrtf(fmaxf(var, 0.f) + EPSV);
  }
  {
    float* c1 = &cs[0][0];
    c1[tid] = 0.f;
    if(tid < 64) c1[256 + tid] = 0.f;
  }
  __syncthreads();
  float sh[4]  = {0,0,0,0}, sh2[4] = {0,0,0,0};
  float sz[4]  = {0,0,0,0}, sz2[4] = {0,0,0,0}, shz[4] = {0,0,0,0};
  #pragma unroll
  for(int c = 0; c < 4; c++){
    size_t obase_off = ((size_t)(b*2 + br)*16384 + (r0 & 16383) + c*64)*64;
    const float* zbase = z + obase_off;
    float zr[16];
    #pragma unroll
    for(int t = 0; t < 4; t++)
      #pragma unroll
      for(int r = 0; r < 4; r++)
        zr[t*4 + r] = zbase[(size_t)(w*16 + quad*4 + r)*64 + t*16 + l15];
    f32x4 acc2[4];
    #pragma unroll
    for(int t = 0; t < 4; t++) acc2[t] = (f32x4){0.f,0.f,0.f,0.f};
    for(int ch = 0; ch < 4; ch++){
      #pragma unroll
      for(int t = 0; t < 4; t++){
        int fid = (ch*4 + t)*2;
        short8 b0 = *(const short8*)(Ws1 + fid*512 + lane*8);
        short8 b1 = *(const short8*)(Ws1 + fid*512 + 512 + lane*8);
        f32x4 acc = {0.f,0.f,0.f,0.f};
        acc = __builtin_amdgcn_mfma_f32_16x16x32_bf16(a0r[c], b0, acc, 0, 0, 0);
        acc = __builtin_amdgcn_mfma_f32_16x16x32_bf16(a1r[c], b1, acc, 0, 0, 0);
        int n = ch*64 + t*16 + l15, gi = n >> 4;
        float w1v = pb[256 + n];
        float gwv = w1v * rs1[gi];
        float gbv = (pb[n] - mu1[gi])*rs1[gi]*w1v + pb[512 + n];
        #pragma unroll
        for(int r = 0; r < 4; r++){
          float hv = acc[r]*gwv + gbv;
          hv = hv > 0.f ? hv : 0.f;
          Hn[w*16 + quad*4 + r][t*16 + l15] = f2bs(hv);
        }
      }
      short8 ha0 = *(short8*)&Hn[myrow][quad*8];
      short8 ha1 = *(short8*)&Hn[myrow][32 + quad*8];
      #pragma unroll
      for(int t = 0; t < 4; t++){
        int fid = (ch*4 + t)*2;
        short8 b0 = *(const short8*)(Ws2 + fid*512 + lane*8);
        short8 b1 = *(const short8*)(Ws2 + fid*512 + 512 + lane*8);
        acc2[t] = __builtin_amdgcn_mfma_f32_16x16x32_bf16(ha0, b0, acc2[t], 0, 0, 0);
        acc2[t] = __builtin_amdgcn_mfma_f32_16x16x32_bf16(ha1, b1, acc2[t], 0, 0, 0);
      }
    }
    unsigned short* hbase = H2 + obase_off;
    #pragma unroll
    for(int t = 0; t < 4; t++){
      int col = t*16 + l15;
      float bias2 = pb[768 + col];
      #pragma unroll
      for(int r = 0; r < 4; r++){
        size_t off = (size_t)(w*16 + quad*4 + r)*64 + col;
        float h2 = acc2[t][r] + bias2;
        float zv = zr[t*4 + r];
        hbase[off] = (unsigned short)f2bs(h2);
        sh[t] += h2; sh2[t] += h2*h2;
        sz[t] += zv; sz2[t] += zv*zv; shz[t] += h2*zv;
      }
    }
  }
  #pragma unroll
  for(int t = 0; t < 4; t++){
    float v0 = sh[t], v1 = sh2[t], v2 = sz[t], v3 = sz2[t], v4 = shz[t];
    v0 += __shfl_xor(v0, 16); v0 += __shfl_xor(v0, 32);
    v1 += __shfl_xor(v1, 16); v1 += __shfl_xor(v1, 32);
    v2 += __shfl_xor(v2, 16); v2 += __shfl_xor(v2, 32);
    v3 += __shfl_xor(v3, 16); v3 += __shfl_xor(v3, 32);
    v4 += __shfl_xor(v4, 16); v4 += __shfl_xor(v4, 32);
    if(quad == 0){
      int ch = t*16 + l15;
      atomicAdd(&cs[0][ch], v0); atomicAdd(&cs[1][ch], v1);
      atomicAdd(&cs[2][ch], v2); atomicAdd(&cs[3][ch], v3);
      atomicAdd(&cs[4][ch], v4);
    }
  }
  __syncthreads();
  float* slab = CS + (size_t)blockIdx.x*320;
  const float* c1 = &cs[0][0];
  slab[tid] = c1[tid];
  if(tid < 64) slab[256 + tid] = c1[256 + tid];
}

// ------- StatB: GN2 params + analytic GN3 stats -> fused affine coeffs ------
__global__ __launch_bounds__(256) void k_statB(const float* __restrict__ CS,
                                               const float* __restrict__ PB,
                                               float* __restrict__ CF){
  __shared__ float chs[5][64];
  __shared__ float mu2s[4], rs2s[4], tg[4], tq[4], mu3s[4], rs3s[4];
  int br = blockIdx.x >> 2, b = blockIdx.x & 3;
  int tid = threadIdx.x;
  const float* base = CS + ((size_t)(br*256 + b*64))*320;
  float* c1 = &chs[0][0];
  for(int v = tid; v < 320; v += 256){
    float s = 0.f;
    for(int k = 0; k < 64; k++) s += base[(size_t)k*320 + v];
    c1[v] = s;
  }
  __syncthreads();
  if(tid < 4){
    float s = 0.f, q = 0.f;
    for(int o = tid*16; o < tid*16 + 16; o++){ s += chs[0][o]; q += chs[1][o]; }
    float mean = s/262144.f, var = q/262144.f - mean*mean;
    mu2s[tid] = mean; rs2s[tid] = rsqrtf(fmaxf(var, 0.f) + EPSV);
    tg[tid] = 0.f; tq[tid] = 0.f;
  }
  __syncthreads();
  const float* pb = PB + br*2048;
  if(tid < 64){
    int o = tid, g = o >> 4;
    float w2v = pb[832 + o], b2v = pb[896 + o];
    float gw = w2v*rs2s[g], gb = b2v - mu2s[g]*rs2s[g]*w2v;
    float Sh = chs[0][o], Sh2 = chs[1][o], Sz = chs[2][o], Sz2 = chs[3][o], Shz = chs[4][o];
    float st = gw*Sh + Sz + 16384.f*gb;
    float sq = gw*gw*Sh2 + Sz2 + 16384.f*gb*gb + 2.f*gw*Shz + 2.f*gw*gb*Sh + 2.f*gb*Sz;
    atomicAdd(&tg[g], st); atomicAdd(&tq[g], sq);
  }
  __syncthreads();
  if(tid < 4){
    float mean = tg[tid]/262144.f, var = tq[tid]/262144.f - mean*mean;
    mu3s[tid] = mean; rs3s[tid] = rsqrtf(fmaxf(var, 0.f) + EPSV);
  }
  __syncthreads();
  if(tid < 64){
    int o = tid, g = o >> 4;
    float w2v = pb[832 + o], b2v = pb[896 + o];
    float gw = w2v*rs2s[g], gb = b2v - mu2s[g]*rs2s[g]*w2v;
    float w3v = pb[960 + o], b3v = pb[1024 + o];
    float gw3 = w3v*rs3s[g], gb3 = b3v - mu3s[g]*rs3s[g]*w3v;
    float* cf = CF + (size_t)(br*4 + b)*192;
    cf[o]       = gw*gw3;          // alpha (h2 coefficient)
    cf[64 + o]  = gw3;             // beta  (z coefficient)
    cf[128 + o] = gb*gw3 + gb3;    // gamma
  }
}

// ------- Final: out = alpha*h2(bf16) + beta*z + gamma ------------------------
__global__ __launch_bounds__(256) void k_final(const float* __restrict__ z,
                                               const float* __restrict__ CF,
                                               const unsigned short* __restrict__ H2,
                                               float* __restrict__ out){
  int tid = blockIdx.x*256 + threadIdx.x;
  const float4* z4 = (const float4*)z;
  const float4* cf4 = (const float4*)CF;
  const ushort4* h4 = (const ushort4*)H2;
  float4* o4 = (float4*)out;
  #pragma unroll
  for(int r = 0; r < 8; r++){
    int i4 = r*262144 + tid;
    int s = i4 >> 18;                 // (b*2+br)
    int b = s >> 1, br = s & 1;
    int cbase = (br*4 + b)*48 + (i4 & 15);
    float4 a = cf4[cbase], bb = cf4[cbase + 16], g = cf4[cbase + 32];
    ushort4 hu = h4[i4];
    float4 zv = z4[i4];
    o4[i4] = make_float4(s2f((short)hu.x)*a.x + zv.x*bb.x + g.x,
                         s2f((short)hu.y)*a.y + zv.y*bb.y + g.y,
                         s2f((short)hu.z)*a.z + zv.z*bb.z + g.z,
                         s2f((short)hu.w)*a.w + zv.w*bb.w + g.w);
  }
}

extern "C" void kernel_launch(void* const* d_in, const int* in_sizes, int n_in,
                              void* d_out, int out_size, void* d_ws, size_t ws_size,
                              hipStream_t stream){
  const float* z   = (const float*)d_in[0];
  const float* x   = (const float*)d_in[1];
  const float* fw1 = (const float*)d_in[2];
  const float* fw2 = (const float*)d_in[3];
  char* ws = (char*)d_ws;
  // workspace layout (byte offsets)
  float2* Y   = (float2*)(ws + 0);           // 4,194,304 B  [b][ky][m][i]
  float2* X2  = (float2*)(ws + 4194304);     // 1,048,576 B
  float2* T   = Y;                           // alias: Y dead after k_xdft
  bf16*   XO  = (bf16*)(ws + 5242880);       // 8,388,608 B
  float*  ST  = (float*)(ws + 13631488);     // 2,048 B
  short*  W1g = (short*)(ws + 13633536);     // 65,536 B
  short*  W2g = (short*)(ws + 13699072);     // 65,536 B
  float2* TWY = (float2*)(ws + 13764608);    // 16,384 B
  float2* TWX = (float2*)(ws + 13780992);    // 32,768 B
  float*  PB  = (float*)(ws + 13813760);     // 16,384 B
  float2* FWT = (float2*)(ws + 13830144);    // 16,777,216 B -> ends 30,607,360
  float*  CS  = (float*)(ws + 14878720);     // 655,360 B (512 slabs x 320) [FWT-alias, dead after mix]
  float*  CF  = (float*)(ws + 15927296);     // 6,144 B   (8 x 192)         [FWT-alias]
  unsigned short* H2 = (unsigned short*)(ws + 16777216);  // 16,777,216 B bf16 h2
  float*  Cg  = (float*)(ws + 33554432);     // 65,536 B  (4 x 64 x 64), zeroed in k_xdft
  float*  SX  = Cg + 16384;                  // 1,024 B   (4 x 64), plain-written in scov

  const float* p[20];
  for(int i = 0; i < 20; i++) p[i] = (const float*)d_in[4 + i];

  k_prep_ydft<<<1314, 256, 0, stream>>>(x, z, fw1, fw2, FWT,
                                  p[0],p[1],p[2],p[3],p[4],p[5],p[6],p[7],p[8],p[9],
                                  p[10],p[11],p[12],p[13],p[14],p[15],p[16],p[17],p[18],p[19],
                                  W1g, W2g, TWY, TWX, PB, ST, Y);
  k_xdft<<<256, 512, 0, stream>>>(Y, TWX, X2, Cg);
  k_mix<<<256, 512, 0, stream>>>(X2, FWT);
  k_inv1scov<<<272, 512, 0, stream>>>(X2, TWX, Cg, SX, T);
  k_stat<<<128, 256, 0, stream>>>(Cg, SX, W1g, PB, ST);
  k_inv2<<<512, 256, 0, stream>>>(T, TWY, XO);
  k_ffmain<<<512, 256, 0, stream>>>(XO, W1g, W2g, PB, ST, z, CS, H2);
  k_statB<<<8, 256, 0, stream>>>(CS, PB, CF);
  k_final<<<1024, 256, 0, stream>>>(z, CF, H2, (float*)d_out);
}